// Round 4
// baseline (255.517 us; speedup 1.0000x reference)
//
#include <hip/hip_runtime.h>
#include <stdint.h>

// VectorQuantizer — bit-exact replication of the fp32 numpy reference.
//   d = sum(z*z,1)[:,None] + sum(c*c,1)[None,:] - 2.0*einsum('nc,kc->nk',z,c)
// sums: numpy pairwise_sum n=64 (8 accumulators + fixed tree). einsum: AVX512
// order — 16 chained-FMA lanes over 4 blocks of 16, then reduce_add tree.
//
// Round 4 theory: rounds 0-3 all ~137-155us because the inline-asm VOP3P
// path ("v" constraints) forced v_accvgpr_read copies for the AGPR-parked
// zz array on EVERY use (~30% VALU inflation; VGPR_Count pinned at 48-84 =
// arch file only, across every waves_per_eu setting). On gfx950 VALU can
// source AGPRs DIRECTLY — plain fmaf() (v_fma_f32, 2cy/wave64) has the same
// cycle cost as v_pk_fma_f32 (4cy, half-rate per component) with zero copy
// tax and full compiler scheduling freedom. Also: the 4-way k-split gave
// each wave a 32KB codebook slice -> 4 slices thrash the ~16KB scalar cache
// -> every row s_load missed to L2 (~200cy exposed). All waves now walk
// k=0..511 in the same order: resident waves draft in sL1 (64-row capacity),
// misses collapse to first-toucher.
//
// Structure: 1 point/lane, 64-thread blocks (1 wave), 2048 blocks, each wave
// scans ALL 512 codes (no k-split, no combine). Argmin: ascending scan,
// strict < keeps first occurrence. Codebook row via wave-uniform s_load
// (SGPRs, zero VALU cost); cnorm via LDS broadcast read.

#pragma clang fp contract(off)

#define KCODES 512
#define CDIM 64
#define HW 4096              // 64*64
#define ZQ_ELEMS 8388608     // 32*64*64*64

// np.sum(row*row): pairwise_sum n=64 replica (products pre-rounded), one row
static __device__ __forceinline__ float cnorm_row(const float* __restrict__ row) {
    float r[8];
    #pragma unroll
    for (int j = 0; j < 8; ++j) r[j] = row[j] * row[j];
    #pragma unroll
    for (int i = 8; i < 64; i += 8) {
        #pragma unroll
        for (int j = 0; j < 8; ++j) r[j] = r[j] + row[i + j] * row[i + j];
    }
    return ((r[0] + r[1]) + (r[2] + r[3])) + ((r[4] + r[5]) + (r[6] + r[7]));
}

// One-shot: cnorm[512] into workspace. 2 blocks x 256 threads.
__global__ void cnorm_kernel(const float* __restrict__ cb,
                             float* __restrict__ cnorm_out) {
    int k = (int)blockIdx.x * 256 + (int)threadIdx.x;
    if (k < KCODES) cnorm_out[k] = cnorm_row(cb + (size_t)k * CDIM);
}

__global__ __launch_bounds__(64)
void vq_kernel(
    const float* __restrict__ z_e,
    const float* __restrict__ cb,
    const float* __restrict__ cnorm_g,   // precomputed (d_ws) or nullptr
    float* __restrict__ out)
{
    __shared__ float cnorm[KCODES];

    const int lane = (int)threadIdx.x;   // 0..63, one wave per block

    if (cnorm_g) {
        // coalesced 2KB load
        #pragma unroll
        for (int k = lane; k < KCODES; k += 64)
            cnorm[k] = cnorm_g[k];
    } else {
        // fallback (ws too small): in-block compute, bit-identical
        for (int k = lane; k < KCODES; k += 64)
            cnorm[k] = cnorm_row(cb + (size_t)k * CDIM);
    }

    // block = 64 consecutive points, one per lane
    const int n0 = (int)blockIdx.x * 64;
    const int b = n0 / HW;
    const int hw0 = n0 % HW;
    const float* zp = z_e + (size_t)b * CDIM * HW + hw0 + lane;

    // one point per lane: zz[m] = z[channel m]; 64 coalesced 256B loads
    float zz[CDIM];
    #pragma unroll
    for (int m = 0; m < CDIM; ++m)
        zz[m] = zp[(size_t)m * HW];

    // np.sum(z*z, axis=1): pairwise replica (products pre-rounded)
    float sz;
    {
        float r[8];
        #pragma unroll
        for (int j = 0; j < 8; ++j) r[j] = zz[j] * zz[j];
        #pragma unroll
        for (int i = 8; i < 64; i += 8) {
            #pragma unroll
            for (int j = 0; j < 8; ++j) r[j] = r[j] + zz[i + j] * zz[i + j];
        }
        sz = ((r[0] + r[1]) + (r[2] + r[3])) + ((r[4] + r[5]) + (r[6] + r[7]));
    }

    __syncthreads();

    float best = 3.4e38f;
    int bk = 0;

    for (int k = 0; k < KCODES; ++k) {
        const float* ck = cb + (size_t)k * CDIM;   // k wave-uniform -> s_load

        // einsum AVX512 order: 16 chained-FMA lanes over 4 blocks of 16
        // v[l] = fma(z[l],c[l], fma(z[16+l],c[16+l], fma(z[32+l],c[32+l],
        //        fma(z[48+l],c[48+l], 0))))
        float v[16];
        #pragma unroll
        for (int l = 0; l < 16; ++l)
            v[l] = fmaf(zz[l], ck[l],
                     fmaf(zz[16 + l], ck[16 + l],
                       fmaf(zz[32 + l], ck[32 + l],
                         fmaf(zz[48 + l], ck[48 + l], 0.f))));

        // reduce_add tree: e[l]=v[l]+v[8+l]; f[l]=e[l]+e[4+l];
        // dot = (f0+f2) + (f1+f3)
        float e[8];
        #pragma unroll
        for (int l = 0; l < 8; ++l) e[l] = v[l] + v[8 + l];
        float f[4];
        #pragma unroll
        for (int l = 0; l < 4; ++l) f[l] = e[l] + e[4 + l];
        float g0 = f[0] + f[2];
        float g1 = f[1] + f[3];
        float dot = g0 + g1;

        float A = sz + cnorm[k];               // fl(sz + sc_k)
        float d = fmaf(dot, -2.f, A);          // == fl(A - 2*dot): 2*dot exact

        if (d < best) { best = d; bk = k; }    // strict <: first occurrence
    }

    // indices (as float32, second output region)
    out[ZQ_ELEMS + n0 + lane] = (float)bk;

    // z_q: per-lane gather of the winning row (16x dwordx4, L1/L2-resident
    // 128KB codebook), 64 coalesced 4B/lane stores
    const float* row = cb + (size_t)bk * CDIM;
    float* op = out + (size_t)b * CDIM * HW + hw0 + lane;
    #pragma unroll
    for (int c4 = 0; c4 < 16; ++c4) {
        float4 t = ((const float4*)row)[c4];   // rows are 256B-aligned
        op[(size_t)(4 * c4 + 0) * HW] = t.x;
        op[(size_t)(4 * c4 + 1) * HW] = t.y;
        op[(size_t)(4 * c4 + 2) * HW] = t.z;
        op[(size_t)(4 * c4 + 3) * HW] = t.w;
    }
}

extern "C" void kernel_launch(void* const* d_in, const int* in_sizes, int n_in,
                              void* d_out, int out_size, void* d_ws, size_t ws_size,
                              hipStream_t stream) {
    const float* z_e = (const float*)d_in[0];
    const float* cb  = (const float*)d_in[1];
    float* out = (float*)d_out;

    float* cnorm_ws = nullptr;
    if (ws_size >= KCODES * sizeof(float)) {
        cnorm_ws = (float*)d_ws;
        cnorm_kernel<<<dim3(2), dim3(256), 0, stream>>>(cb, cnorm_ws);
    }
    vq_kernel<<<dim3(2048), dim3(64), 0, stream>>>(z_e, cb, cnorm_ws, out);
}

// Round 5
// 195.754 us; speedup vs baseline: 1.3053x; 1.3053x over previous
//
#include <hip/hip_runtime.h>
#include <stdint.h>

// VectorQuantizer — bit-exact replication of the fp32 numpy reference.
//   d = sum(z*z,1)[:,None] + sum(c*c,1)[None,:] - 2.0*einsum('nc,kc->nk',z,c)
// sums: numpy pairwise_sum n=64 (8 accumulators + fixed tree). einsum: AVX512
// order — 16 chained-FMA lanes over 4 blocks of 16, then reduce_add tree.
//
// Round 5 = r3 structure + r4 inner loop. The two prior rounds were clean
// ablations:
//   r3 (4-wave k-split, pk-asm inner):  137us, busy 92us — split gives 8192
//       waves (latency hidden) but asm "v" constraints tax every zz use
//       with v_accvgpr_read copies.
//   r4 (no split, scalar fmaf inner):   190us, busy 82us — scalar v_fma_f32
//       (2cy, same rate as pk per component, zero copy tax) is the leanest
//       loop yet, but 2048 waves total (2/SIMD) exposes the s_load latency.
// This round combines: 4-wave k-split (8192 waves) + scalar fmaf loop.
// Scalar sequence == packed sequence value-for-value (r4 passed absmax=0).
// No occupancy attributes: live ~90 regs, allocator default (~5 waves/SIMD).
//
// Structure: 1 point/lane, 4-wave k-split (wave g: k in [128g,128g+128)),
// block = 64 points, 2048 blocks. Codebook row via wave-uniform s_load;
// cnorm precomputed once into d_ws, broadcast-read from LDS. Argmin over
// ascending disjoint k-ranges combined with strict < (first occurrence).

#pragma clang fp contract(off)

#define KCODES 512
#define CDIM 64
#define HW 4096              // 64*64
#define ZQ_ELEMS 8388608     // 32*64*64*64

// np.sum(row*row): pairwise_sum n=64 replica (products pre-rounded), one row
static __device__ __forceinline__ float cnorm_row(const float* __restrict__ row) {
    float r[8];
    #pragma unroll
    for (int j = 0; j < 8; ++j) r[j] = row[j] * row[j];
    #pragma unroll
    for (int i = 8; i < 64; i += 8) {
        #pragma unroll
        for (int j = 0; j < 8; ++j) r[j] = r[j] + row[i + j] * row[i + j];
    }
    return ((r[0] + r[1]) + (r[2] + r[3])) + ((r[4] + r[5]) + (r[6] + r[7]));
}

// One-shot: cnorm[512] into workspace. 2 blocks x 256 threads.
__global__ void cnorm_kernel(const float* __restrict__ cb,
                             float* __restrict__ cnorm_out) {
    int k = (int)blockIdx.x * 256 + (int)threadIdx.x;
    if (k < KCODES) cnorm_out[k] = cnorm_row(cb + (size_t)k * CDIM);
}

__global__ __launch_bounds__(256)
void vq_kernel(
    const float* __restrict__ z_e,
    const float* __restrict__ cb,
    const float* __restrict__ cnorm_g,   // precomputed (d_ws) or nullptr
    float* __restrict__ out)
{
    __shared__ float cnorm[KCODES];
    __shared__ float dcand[4 * 64];
    __shared__ int   kcand[4 * 64];

    if (cnorm_g) {
        // coalesced 2KB load: 2 x 4B/lane, stride-1
        #pragma unroll
        for (int k = (int)threadIdx.x; k < KCODES; k += 256)
            cnorm[k] = cnorm_g[k];
    } else {
        // fallback (ws too small): in-block compute, bit-identical
        for (int k = (int)threadIdx.x; k < KCODES; k += 256)
            cnorm[k] = cnorm_row(cb + (size_t)k * CDIM);
    }

    // block = 64 consecutive points; wave g covers k in [128g, 128g+128)
    const int lane = (int)threadIdx.x & 63;
    const int g = __builtin_amdgcn_readfirstlane((int)threadIdx.x >> 6);
    const int n0 = (int)blockIdx.x * 64;
    const int b = n0 / HW;
    const int hw0 = n0 % HW;
    const float* zp = z_e + (size_t)b * CDIM * HW + hw0 + lane;

    // one point per lane: zz[m] = z[channel m]; 64 coalesced 256B loads
    float zz[CDIM];
    #pragma unroll
    for (int m = 0; m < CDIM; ++m)
        zz[m] = zp[(size_t)m * HW];

    // np.sum(z*z, axis=1): pairwise replica (products pre-rounded)
    float sz;
    {
        float r[8];
        #pragma unroll
        for (int j = 0; j < 8; ++j) r[j] = zz[j] * zz[j];
        #pragma unroll
        for (int i = 8; i < 64; i += 8) {
            #pragma unroll
            for (int j = 0; j < 8; ++j) r[j] = r[j] + zz[i + j] * zz[i + j];
        }
        sz = ((r[0] + r[1]) + (r[2] + r[3])) + ((r[4] + r[5]) + (r[6] + r[7]));
    }

    __syncthreads();

    float best = 3.4e38f;
    int bk = 0;
    const int k0 = g * 128;

    for (int i = 0; i < 128; ++i) {
        const int k = k0 + i;                      // wave-uniform -> s_load
        const float* ck = cb + (size_t)k * CDIM;

        // einsum AVX512 order: 16 chained-FMA lanes over 4 blocks of 16
        // v[l] = fma(z[l],c[l], fma(z[16+l],c[16+l], fma(z[32+l],c[32+l],
        //        fma(z[48+l],c[48+l], 0))))
        float v[16];
        #pragma unroll
        for (int l = 0; l < 16; ++l)
            v[l] = fmaf(zz[l], ck[l],
                     fmaf(zz[16 + l], ck[16 + l],
                       fmaf(zz[32 + l], ck[32 + l],
                         fmaf(zz[48 + l], ck[48 + l], 0.f))));

        // reduce_add tree: e[l]=v[l]+v[8+l]; f[l]=e[l]+e[4+l];
        // dot = (f0+f2) + (f1+f3)
        float e[8];
        #pragma unroll
        for (int l = 0; l < 8; ++l) e[l] = v[l] + v[8 + l];
        float f[4];
        #pragma unroll
        for (int l = 0; l < 4; ++l) f[l] = e[l] + e[4 + l];
        float g0 = f[0] + f[2];
        float g1 = f[1] + f[3];
        float dot = g0 + g1;

        float A = sz + cnorm[k];               // fl(sz + sc_k)
        float d = fmaf(dot, -2.f, A);          // == fl(A - 2*dot): 2*dot exact

        if (d < best) { best = d; bk = k; }    // strict <: first occurrence
    }

    dcand[g * 64 + lane] = best;
    kcand[g * 64 + lane] = bk;
    __syncthreads();

    // combine over ascending k-ranges (strict < keeps first occurrence)
    float bd = dcand[lane];
    int bi = kcand[lane];
    #pragma unroll
    for (int gg = 1; gg < 4; ++gg) {
        float d2 = dcand[gg * 64 + lane];
        int   k2 = kcand[gg * 64 + lane];
        if (d2 < bd) { bd = d2; bi = k2; }
    }

    // indices (as float32, second output region) — wave 0 only
    if (g == 0) out[ZQ_ELEMS + n0 + lane] = (float)bi;

    // z_q: wave g writes channels [16g, 16g+16); coalesced 4B/lane stores
    const float* row = cb + (size_t)bi * CDIM;
    float* op = out + (size_t)b * CDIM * HW + hw0 + lane;
    #pragma unroll
    for (int c = 0; c < 16; ++c) {
        const int ch = g * 16 + c;
        op[(size_t)ch * HW] = row[ch];
    }
}

extern "C" void kernel_launch(void* const* d_in, const int* in_sizes, int n_in,
                              void* d_out, int out_size, void* d_ws, size_t ws_size,
                              hipStream_t stream) {
    const float* z_e = (const float*)d_in[0];
    const float* cb  = (const float*)d_in[1];
    float* out = (float*)d_out;

    float* cnorm_ws = nullptr;
    if (ws_size >= KCODES * sizeof(float)) {
        cnorm_ws = (float*)d_ws;
        cnorm_kernel<<<dim3(2), dim3(256), 0, stream>>>(cb, cnorm_ws);
    }
    vq_kernel<<<dim3(2048), dim3(256), 0, stream>>>(z_e, cb, cnorm_ws, out);
}